// Round 9
// baseline (56536.768 us; speedup 1.0000x reference)
//
#include <hip/hip_runtime.h>
#include <hip/hip_bf16.h>

// Persistent cooperative RNN kernel for MI355X (gfx950) — barrier-free
// epoch-tagged dataflow. 256 WGs x 512 threads, 1 WG/CU (~150KB LDS).
// Each WG owns 4 hidden rows => 16 gate rows of every 4H weight matrix.
// Cross-WG values are 8-byte (f32 value, u32 epoch) pairs, consumed by
// polling coherent (sc0 sc1) 16B loads.
// ROUND-9 CHANGE (theory: leg cost = producer store-VISIBILITY lag):
//   stp() now uses global_atomic_swap_x2 ... sc1 instead of a plain
//   agent-scope store. Atomics execute AT the device coherence point (L3),
//   so the value is visible to cross-XCD sc0/sc1 polls in one trip — no
//   lazy write-back. Every stp has a unique address + single writer, so
//   there is zero RMW serialization (unlike round 1's shared counters).
//   Backoff sleep shortened (max s_sleep(4)) since detect quantization now
//   matters relative to the faster leg.
// Round-8 structure kept: no split-K partials — ds/f producer WGs (w16-39)
// compute outputs directly from the dh_i broadcast via hw_dot on global
// clsW/futW rows; dh3 broadcast via DD3. WRITE_SIZE 6.4GB->0.15GB confirmed.
// Register notes (rounds 2-6): toolchain caps this kernel at 128 VGPRs
// regardless of attributes; register-resident cls/fut weights always spill.
// fw[64] (fusW rows) fits without spill — proven in rounds 0/7/8.

typedef unsigned short u16t;
typedef unsigned int u32t;
typedef unsigned long long u64t;

#define TSTEPS 2045
#define NWG 256
#define NTHR 512
#define SPINCAP 8192

// d_ws float offsets (all pair arrays: 2 floats per element)
#define HENC  0        // [par][1024 pairs]  enc h
#define CENC  4096     // [par][1024 pairs]  enc c
#define DHX   8192     // [par][1024 pairs]  head dhx
#define DD1   12288    // [par][1024 pairs]  dec h1
#define DD2   16384    // [par][1024 pairs]  dec h2
#define DD3   20480    // [par][1024 pairs]  dec h3
#define SFF   24576    // [par][3 ph][128 pairs]   ds(0..63)|f(64..127)

struct Params {
  const void *X, *eWih, *eWhh, *ebih, *ebhh, *dWih, *dWhh, *dbih, *dbhh,
             *hxW, *hxb, *cxW, *cxb, *fusW, *fusb_g, *futW, *futb_g, *clsW, *clsb_g;
  float* ws;
  void* out;
};

struct SharedMem {
  alignas(16) float encW[16 * 1152];   // [row][Wih(128)|Whh(1024)] f32, 73728B
  alignas(16) u16t  decW[16 * 2048];   // [row][Wih(1024)|Whh(1024)] bf16, 65536B
  alignas(16) float xs[2048];          // staged vectors for dots
  alignas(16) float xsf[128];          // R1 fusion input [x(64)|fut(64)]
  float clsb[64], futb[64], fut_acc[64], dsbuf[64], fv3[64], xnext[64];
  float bias_e[16], bias_d[16], g16[16];
  float dcx_s[4], encc[4], hxb4[4], cxb4[4];
  int bail;
  int badcnt;
};

__device__ __forceinline__ float bfu(u16t u){
  union { u32t i; float f; } v; v.i = ((u32t)u) << 16; return v.f;
}
__device__ __forceinline__ u32t fbits(float f){
  union { float f; u32t u; } c; c.f = f; return c.u;
}
__device__ __forceinline__ u16t bf16bits(float v){
  __hip_bfloat16 b = __float2bfloat16(v);
  union { __hip_bfloat16 b; u16t u; } c; c.b = b; return c.u;
}
template<bool F32>
__device__ __forceinline__ float ldE(const void* p, int i){
  if (F32) return ((const float*)p)[i];
  return bfu(((const u16t*)p)[i]);
}
template<bool F32>
__device__ __forceinline__ u16t ldB(const void* p, int i){
  if (F32) return bf16bits(((const float*)p)[i]);
  return ((const u16t*)p)[i];
}
template<bool F32>
__device__ __forceinline__ void stO(void* p, int i, float v){
  if (F32) ((float*)p)[i] = v;
  else     ((u16t*)p)[i] = bf16bits(v);
}
__device__ __forceinline__ float sigm(float x){ return 1.f / (1.f + __expf(-x)); }
__device__ __forceinline__ float tanhx(float x){
  float e = __expf(-2.f * fabsf(x));
  float t = (1.f - e) / (1.f + e);
  return copysignf(t, x);
}
// Light escalating backoff: keep detect quantization small now that
// visibility is fast (max ~107ns).
__device__ __forceinline__ void backoff(int sp){
  if (sp > 16)     __builtin_amdgcn_s_sleep(4);   // ~107ns
  else if (sp > 4) __builtin_amdgcn_s_sleep(1);   // ~27ns
}
// Tagged-pair publish: (value, epoch) via 64-bit device-scope atomic swap.
// Atomics execute at L3 (device coherence point) -> immediately visible to
// cross-XCD sc0/sc1 polls; unique address + single writer -> no contention.
__device__ __forceinline__ void stp(float* rowbase, int idx, float v, u32t ep){
  u64t u = (u64t)fbits(v) | ((u64t)ep << 32);
  u64t* ptr = (u64t*)rowbase + idx;
  asm volatile("global_atomic_swap_x2 %0, %1, off sc1"
               :: "v"(ptr), "v"(u) : "memory");
}
// Coherent 16B load (device coherence point).
__device__ __forceinline__ float4 ld4c(const float* p){
  float4 r;
  asm volatile("global_load_dwordx4 %0, %1, off sc0 sc1\n\t"
               "s_waitcnt vmcnt(0)"
               : "=&v"(r) : "v"(p) : "memory");
  return r;
}
// Two coherent 16B loads, single wait.
__device__ __forceinline__ void ld4c2(const float* p0, const float* p1,
                                      float4& a, float4& b){
  asm volatile(
    "global_load_dwordx4 %0, %2, off sc0 sc1\n\t"
    "global_load_dwordx4 %1, %3, off sc0 sc1\n\t"
    "s_waitcnt vmcnt(0)"
    : "=&v"(a), "=&v"(b)
    : "v"(p0), "v"(p1)
    : "memory");
}
// Poll one quad (2 tagged pairs) until both tags == ep.
__device__ __forceinline__ float2 poll2(const float* q, u32t ep, int* bail){
  float4 r; int sp = 0;
  for (;;){
    r = ld4c(q);
    if (fbits(r.y) == ep && fbits(r.w) == ep) break;
    if (*bail) break;
    if (++sp > SPINCAP){ *bail = 1; break; }
    backoff(sp);
  }
  return float2{r.x, r.z};
}

// Half-wave (32 lanes) dot of GLOBAL weight row with f32 x (LDS).
template<bool F32>
__device__ __forceinline__ float hw_dot(const void* wbase, long off,
                                        const float* __restrict__ x,
                                        int K, int lane){
  float acc = 0.f;
  if (F32){
    const float* w = (const float*)wbase + off;
    for (int c = lane * 4; c < K; c += 128){
      float4 wv = *(const float4*)(w + c);
      float4 xv = *(const float4*)(x + c);
      acc = fmaf(wv.x, xv.x, acc); acc = fmaf(wv.y, xv.y, acc);
      acc = fmaf(wv.z, xv.z, acc); acc = fmaf(wv.w, xv.w, acc);
    }
  } else {
    const u16t* w = (const u16t*)wbase + off;
    for (int c = lane * 4; c < K; c += 128){
      ushort4 wv = *(const ushort4*)(w + c);
      float4  xv = *(const float4*)(x + c);
      acc = fmaf(bfu(wv.x), xv.x, acc); acc = fmaf(bfu(wv.y), xv.y, acc);
      acc = fmaf(bfu(wv.z), xv.z, acc); acc = fmaf(bfu(wv.w), xv.w, acc);
    }
  }
  #pragma unroll
  for (int o = 16; o; o >>= 1) acc += __shfl_xor(acc, o, 64);
  return acc;
}

// Un-reduced per-lane dot partial (half-wave, stride 128); reduce with wred.
__device__ __forceinline__ float dotnr_f32(const float* __restrict__ w,
                                           const float* __restrict__ x,
                                           int K, int lane){
  float acc = 0.f;
  for (int c = lane * 4; c < K; c += 128){
    float4 wv = *(const float4*)(w + c);
    float4 xv = *(const float4*)(x + c);
    acc = fmaf(wv.x, xv.x, acc); acc = fmaf(wv.y, xv.y, acc);
    acc = fmaf(wv.z, xv.z, acc); acc = fmaf(wv.w, xv.w, acc);
  }
  return acc;
}
__device__ __forceinline__ float wred(float a){
  #pragma unroll
  for (int o = 16; o; o >>= 1) a += __shfl_xor(a, o, 64);
  return a;
}

__device__ __forceinline__ float lds_dot_bf16(const u16t* __restrict__ w,
                                              const float* __restrict__ x,
                                              int K, int lane){
  float acc = 0.f;
  for (int c = lane * 8; c < K; c += 256){
    uint4  wv = *(const uint4*)(w + c);
    float4 x0 = *(const float4*)(x + c);
    float4 x1 = *(const float4*)(x + c + 4);
    acc = fmaf(bfu((u16t)(wv.x & 0xffff)), x0.x, acc);
    acc = fmaf(bfu((u16t)(wv.x >> 16)),    x0.y, acc);
    acc = fmaf(bfu((u16t)(wv.y & 0xffff)), x0.z, acc);
    acc = fmaf(bfu((u16t)(wv.y >> 16)),    x0.w, acc);
    acc = fmaf(bfu((u16t)(wv.z & 0xffff)), x1.x, acc);
    acc = fmaf(bfu((u16t)(wv.z >> 16)),    x1.y, acc);
    acc = fmaf(bfu((u16t)(wv.w & 0xffff)), x1.z, acc);
    acc = fmaf(bfu((u16t)(wv.w >> 16)),    x1.w, acc);
  }
  #pragma unroll
  for (int o = 16; o; o >>= 1) acc += __shfl_xor(acc, o, 64);
  return acc;
}

// Direct ds/f production: 16 outputs o=(w&7)*16+hw from the dh broadcast
// already staged in LDS (xs[1024:2048]), weights from global (L2-hot).
// o<64: ds -> out (+ SFF broadcast if ph<2). o>=64: f -> SFF broadcast.
template<bool F32>
__device__ __forceinline__ void produce_sf(const Params& p, float* ws,
                                           SharedMem& S, int ph, int par,
                                           u32t ep, int t, int w, int hw,
                                           int lane){
  const int o = (w & 7) * 16 + hw;
  float* sf = ws + SFF + (par * 3 + ph) * 256;
  if (o < 64){
    float s = hw_dot<F32>(p.clsW, (long)o * 1024, S.xs + 1024, 1024, lane)
            + S.clsb[o];
    if (lane == 0){
      stO<F32>(p.out, TSTEPS * 64 + (t * 3 + ph) * 64 + o, s);
      if (ph < 2) stp(sf, o, s, ep);
    }
  } else {
    float s = fmaxf(hw_dot<F32>(p.futW, (long)(o - 64) * 1024, S.xs + 1024, 1024, lane)
                    + S.futb[o - 64], 0.f);
    if (lane == 0) stp(sf, o, s, ep);
  }
}

template<bool F32>
__device__ void run(const Params& p, SharedMem& S){
  const int tid  = threadIdx.x;
  const int w    = blockIdx.x;
  const int hw   = tid >> 5;            // half-wave 0..15 -> one gate row each
  const int lane = tid & 31;
  const long grow = (long)((hw >> 2) * 1024 + 4 * w + (hw & 3));  // gate row
  float* ws = p.ws;

  // ---------- startup: stage per-WG weights into LDS ----------
  {
    float* er = S.encW + hw * 1152;
    for (int c = lane; c < 128; c += 32)  er[c]       = ldE<F32>(p.eWih, (int)(grow * 128 + c));
    for (int c = lane; c < 1024; c += 32) er[128 + c] = ldE<F32>(p.eWhh, (int)(grow * 1024 + c));
    u16t* dr = S.decW + hw * 2048;
    for (int c = lane; c < 1024; c += 32){
      dr[c]        = ldB<F32>(p.dWih, (int)(grow * 1024 + c));
      dr[1024 + c] = ldB<F32>(p.dWhh, (int)(grow * 1024 + c));
    }
  }
  // fus_W rows for this thread's two h outputs -> registers (proven: no spill)
  u32t fw[64];
  float fusb0, fusb1;
  {
    int h0 = 2 * tid, h1 = 2 * tid + 1;
    #pragma unroll
    for (int o = 0; o < 64; ++o){
      u16t lo = ldB<F32>(p.fusW, h0 * 64 + o);
      u16t hi = ldB<F32>(p.fusW, h1 * 64 + o);
      fw[o] = ((u32t)hi << 16) | lo;
    }
    fusb0 = ldE<F32>(p.fusb_g, h0);
    fusb1 = ldE<F32>(p.fusb_g, h1);
  }
  if (tid < 64){
    S.clsb[tid] = ldE<F32>(p.clsb_g, tid);
    S.futb[tid] = ldE<F32>(p.futb_g, tid);
    S.fut_acc[tid] = 0.f;
  }
  if (tid < 16){
    int gr = (tid >> 2) * 1024 + 4 * w + (tid & 3);
    S.bias_e[tid] = ldE<F32>(p.ebih, gr) + ldE<F32>(p.ebhh, gr);
    S.bias_d[tid] = ldE<F32>(p.dbih, gr) + ldE<F32>(p.dbhh, gr);
  }
  if (tid < 4){
    S.hxb4[tid] = ldE<F32>(p.hxb, 4 * w + tid);
    S.cxb4[tid] = ldE<F32>(p.cxb, 4 * w + tid);
    S.encc[tid] = 0.f;
  }
  float enc_pre = 0.f;   // per-lane partial of encWhh @ h(t-1); h(-1)=0
  __syncthreads();

  for (int t = 0; t < TSTEPS; ++t){
    const int  par  = t & 1;
    const int  ppar = par ^ 1;
    const u32t ep   = (u32t)(t + 1);
    const u32t epv  = (u32t)t;            // tag of previous step's values

    // ============ R1: encoder gates (h part carried in enc_pre) ============
    if (t > 0 && tid < 32){               // f3 pairs: SF[ppar][ph2] quads 32..63
      const float* base = ws + SFF + (ppar * 3 + 2) * 256;
      float2 v = poll2(base + (32 + tid) * 4, epv, &S.bail);
      S.fv3[2 * tid] = v.x; S.fv3[2 * tid + 1] = v.y;
    }
    __syncthreads();
    if (tid < 64){
      S.xsf[tid] = (t == 0) ? ldE<F32>(p.X, tid) : S.xnext[tid];
      float fv = (t > 0) ? (S.fut_acc[tid] + S.fv3[tid]) * (1.f / 3.f) : 0.f;
      S.xsf[64 + tid] = fv;
      S.fut_acc[tid] = 0.f;
    }
    __syncthreads();
    {
      float a = wred(enc_pre + dotnr_f32(S.encW + hw * 1152, S.xsf, 128, lane))
              + S.bias_e[hw];
      if (lane == 0) S.g16[hw] = a;
    }
    __syncthreads();
    if (tid < 4){
      float gi = sigm(S.g16[tid]), gf = sigm(S.g16[4 + tid]),
            gg = tanhx(S.g16[8 + tid]), go = sigm(S.g16[12 + tid]);
      float c = gf * S.encc[tid] + gi * gg;
      float h = go * tanhx(c);
      S.encc[tid] = c;
      stp(ws + HENC + par * 2048, 4 * w + tid, h, ep);
      stp(ws + CENC + par * 2048, 4 * w + tid, c, ep);
    }

    // ============ R2: merged h+c poll; heads dhx/dcx; enc_score; enc_pre ====
    {
      const float* ph_ = ws + HENC + par * 2048 + tid * 4;
      const float* pc_ = ws + CENC + par * 2048 + tid * 4;
      float4 a, b; int sp = 0;
      for (;;){
        ld4c2(ph_, pc_, a, b);
        if (fbits(a.y) == ep && fbits(a.w) == ep &&
            fbits(b.y) == ep && fbits(b.w) == ep) break;
        if (S.bail) break;
        if (++sp > SPINCAP){ S.bail = 1; break; }
        backoff(sp);
      }
      S.xs[2 * tid] = a.x;        S.xs[2 * tid + 1] = a.z;
      S.xs[1024 + 2 * tid] = b.x; S.xs[1025 + 2 * tid] = b.z;
    }
    __syncthreads();
    if (hw < 4){
      float d = fmaxf(hw_dot<F32>(p.hxW, (long)(4 * w + hw) * 1024, S.xs, 1024, lane)
                      + S.hxb4[hw], 0.f);
      if (lane == 0) stp(ws + DHX + par * 2048, 4 * w + hw, d, ep);
    } else if (hw < 8){
      int j = hw - 4;
      float d = fmaxf(hw_dot<F32>(p.cxW, (long)(4 * w + j) * 1024, S.xs + 1024, 1024, lane)
                      + S.cxb4[j], 0.f);
      if (lane == 0) S.dcx_s[j] = d;   // decoder c, reused by all 3 iters (ref bug)
    } else if (w >= 8 && w < 16){      // enc_score: 8 WGs x 8 half-waves
      int r = (w - 8) * 8 + (hw - 8);
      float s = hw_dot<F32>(p.clsW, (long)r * 1024, S.xs, 1024, lane) + S.clsb[r];
      if (lane == 0) stO<F32>(p.out, t * 64 + r, s);
    }
    // next step's encoder Whh@h partial, in R2's shadow (after DHX stp)
    enc_pre = dotnr_f32(S.encW + hw * 1152 + 128, S.xs, 1024, lane);
    __syncthreads();   // protect xs readers (enc_score/dcx) from R3 overwrite

    // ============ R3: decoder iter 1 (fusion_in = 0) ============
    {
      float2 v = poll2(ws + DHX + par * 2048 + tid * 4, ep, &S.bail);
      S.xs[2 * tid] = v.x; S.xs[2 * tid + 1] = v.y;
    }
    __syncthreads();
    {
      float a = lds_dot_bf16(S.decW + hw * 2048 + 1024, S.xs, 1024, lane) + S.bias_d[hw];
      if (lane == 0) S.g16[hw] = a;
    }
    __syncthreads();
    if (tid < 4){
      float gi = sigm(S.g16[tid]), gf = sigm(S.g16[4 + tid]),
            gg = tanhx(S.g16[8 + tid]), go = sigm(S.g16[12 + tid]);
      float c = gf * S.dcx_s[tid] + gi * gg;
      float h = go * tanhx(c);
      stp(ws + DD1 + par * 2048, 4 * w + tid, h, ep);
    }
    if (tid < 64)
      S.xnext[tid] = ldE<F32>(p.X, (t + 1) * 64 + tid);   // prefetch x(t+1)

    // ============ R4/R5: decoder iters 2,3 ============
    for (int di = 2; di <= 3; ++di){
      const int ph = di - 2;               // sf phase produced this round
      // stage dh_{di-1} -> xs[1024:2048]
      {
        const float* dbuf = ws + (di == 2 ? DD1 : DD2) + par * 2048;
        float2 v = poll2(dbuf + tid * 4, ep, &S.bail);
        S.xs[1024 + 2 * tid] = v.x; S.xs[1025 + 2 * tid] = v.y;
      }
      __syncthreads();
      // ds/f producers FIRST (critical path for everyone's fusion), from the
      // dh broadcast just staged — no partials, no scan-detect.
      if (w >= 16 + ph * 8 && w < 24 + ph * 8)
        produce_sf<F32>(p, ws, S, ph, par, ep, t, w, hw, lane);
      float accA = lds_dot_bf16(S.decW + hw * 2048 + 1024, S.xs + 1024, 1024, lane);
      // poll ds/f broadcast
      if (tid < 64){
        const float* sf = ws + SFF + (par * 3 + ph) * 256;
        float2 v = poll2(sf + tid * 4, ep, &S.bail);
        if (tid < 32){ S.dsbuf[2 * tid] = v.x; S.dsbuf[2 * tid + 1] = v.y; }
        else { S.fv3[2 * (tid - 32)] = v.x; S.fv3[2 * (tid - 32) + 1] = v.y; }
      }
      __syncthreads();
      if (tid < 64) S.fut_acc[tid] += S.fv3[tid];
      {   // fusion_in = relu(fus_W @ ds + fus_b), per-thread 2 rows from VGPRs
        float a0 = fusb0, a1 = fusb1;
        #pragma unroll
        for (int o = 0; o < 64; ++o){
          float d = S.dsbuf[o];
          a0 = fmaf(bfu((u16t)(fw[o] & 0xffff)), d, a0);
          a1 = fmaf(bfu((u16t)(fw[o] >> 16)),    d, a1);
        }
        S.xs[2 * tid]     = fmaxf(a0, 0.f);
        S.xs[2 * tid + 1] = fmaxf(a1, 0.f);
      }
      __syncthreads();
      float accB = lds_dot_bf16(S.decW + hw * 2048, S.xs, 1024, lane);
      {
        float a = accA + accB + S.bias_d[hw];
        if (lane == 0) S.g16[hw] = a;
      }
      __syncthreads();
      if (tid < 4){
        float gi = sigm(S.g16[tid]), gf = sigm(S.g16[4 + tid]),
              gg = tanhx(S.g16[8 + tid]), go = sigm(S.g16[12 + tid]);
        float c = gf * S.dcx_s[tid] + gi * gg;
        float h = go * tanhx(c);
        stp(ws + (di == 2 ? DD2 : DD3) + par * 2048, 4 * w + tid, h, ep);
      }
    }
    // ph2 producers: poll DD3, compute ds3 (-> out) and f3 (-> next R1's SFF)
    if (w >= 32 && w < 40){
      {
        float2 v = poll2(ws + DD3 + par * 2048 + tid * 4, ep, &S.bail);
        S.xs[1024 + 2 * tid] = v.x; S.xs[1025 + 2 * tid] = v.y;
      }
      __syncthreads();
      produce_sf<F32>(p, ws, S, 2, par, ep, t, w, hw, lane);
    }
  }
}

__global__ __launch_bounds__(NTHR, 2)
void trn_persist(Params p){
  __shared__ SharedMem S;
  // ---- runtime input-dtype detection from X's bit patterns ----
  if (threadIdx.x == 0){ S.bail = 0; S.badcnt = 0; }
  __syncthreads();
  if (threadIdx.x < 256){
    u16t u = ((const u16t*)p.X)[threadIdx.x];
    int e = (u >> 7) & 0xff;
    if (e == 0 || e >= 141) atomicAdd(&S.badcnt, 1);
  }
  __syncthreads();
  if (S.badcnt >= 3) run<true>(p, S);
  else               run<false>(p, S);
}

extern "C" void kernel_launch(void* const* d_in, const int* in_sizes, int n_in,
                              void* d_out, int out_size, void* d_ws, size_t ws_size,
                              hipStream_t stream){
  Params P;
  P.X      = d_in[0];
  P.eWih   = d_in[1];
  P.eWhh   = d_in[2];
  P.ebih   = d_in[3];
  P.ebhh   = d_in[4];
  P.dWih   = d_in[5];
  P.dWhh   = d_in[6];
  P.dbih   = d_in[7];
  P.dbhh   = d_in[8];
  P.hxW    = d_in[9];
  P.hxb    = d_in[10];
  P.cxW    = d_in[11];
  P.cxb    = d_in[12];
  P.fusW   = d_in[13];
  P.fusb_g = d_in[14];
  P.futW   = d_in[15];
  P.futb_g = d_in[16];
  P.clsW   = d_in[17];
  P.clsb_g = d_in[18];
  P.ws     = (float*)d_ws;
  P.out    = d_out;

  void* args[] = { &P };
  hipLaunchCooperativeKernel((void*)trn_persist, dim3(NWG), dim3(NTHR),
                             args, 0, stream);
}

// Round 10
// 49538.733 us; speedup vs baseline: 1.1413x; 1.1413x over previous
//
#include <hip/hip_runtime.h>
#include <hip/hip_bf16.h>

// Persistent cooperative RNN kernel for MI355X (gfx950) — barrier-free
// epoch-tagged dataflow. 256 WGs x 512 threads, 1 WG/CU (~131KB LDS).
// Each WG owns 4 hidden rows => 16 gate rows of every 4H weight matrix.
// Cross-WG values are 8-byte (f32 value, u32 epoch) pairs via agent-scope
// 64-bit atomic stores, consumed by polling coherent (sc0 sc1) 16B loads.
// TOPOLOGY (fixed): 8 full-grid rendezvous/step — enc-h -> dhx -> dh1 ->
// ds1 -> dh2 -> ds2 -> dh3 -> f3 — each separated by a nonlinearity that
// blocks folding. Round 8 measured ~2.4us/leg; round 9 proved atomic-swap
// publish is SLOWER (visibility is not the cost). This round shaves the
// on-chain compute/streaming inside each leg:
//  - hxW/cxW head rows staged in LDS as bf16 (16KB) — R2's critical dot no
//    longer streams f32 from L2. Paid for by encWhh f32->bf16 (frees 32KB).
//  - ds/f producer WGs (w16-39) self-stage their 16 clsW/futW rows as bf16
//    in workspace at startup (self-write/self-read, no barrier) — halves the
//    producer dot's L2 bytes on the chain.
//  - stp reverted to plain agent store + round-8 backoff (proven best).
// Register notes (rounds 2-6): toolchain caps this kernel at 128 VGPRs
// regardless of attributes; register-resident cls/fut weights always spill.
// fw[64] (fusW rows) fits without spill — proven rounds 0/7/8.

typedef unsigned short u16t;
typedef unsigned int u32t;
typedef unsigned long long u64t;

#define TSTEPS 2045
#define NWG 256
#define NTHR 512
#define SPINCAP 8192

// d_ws float offsets (all pair arrays: 2 floats per element)
#define HENC  0        // [par][1024 pairs]  enc h
#define CENC  4096     // [par][1024 pairs]  enc c
#define DHX   8192     // [par][1024 pairs]  head dhx
#define DD1   12288    // [par][1024 pairs]  dec h1
#define DD2   16384    // [par][1024 pairs]  dec h2
#define DD3   20480    // [par][1024 pairs]  dec h3
#define SFF   24576    // [par][3 ph][128 pairs]   ds(0..63)|f(64..127)
#define BCW   28672    // float offset of producer bf16 rows: [24 wg][16][1024] u16

struct Params {
  const void *X, *eWih, *eWhh, *ebih, *ebhh, *dWih, *dWhh, *dbih, *dbhh,
             *hxW, *hxb, *cxW, *cxb, *fusW, *fusb_g, *futW, *futb_g, *clsW, *clsb_g;
  float* ws;
  void* out;
};

struct SharedMem {
  alignas(16) float encWih[16 * 128];  // f32, 8KB  (x|fut gate cols)
  alignas(16) u16t  encWhh[16 * 1024]; // bf16, 32KB
  alignas(16) u16t  decW[16 * 2048];   // bf16, 64KB [row][Wih(1024)|Whh(1024)]
  alignas(16) u16t  headW[8 * 1024];   // bf16, 16KB: hxW rows(0-3) | cxW rows(4-7)
  alignas(16) float xs[2048];          // staged vectors for dots
  alignas(16) float xsf[128];          // R1 fusion input [x(64)|fut(64)]
  float clsb[64], futb[64], fut_acc[64], dsbuf[64], fv3[64], xnext[64];
  float bias_e[16], bias_d[16], g16[16];
  float dcx_s[4], encc[4], hxb4[4], cxb4[4];
  int bail;
  int badcnt;
};

__device__ __forceinline__ float bfu(u16t u){
  union { u32t i; float f; } v; v.i = ((u32t)u) << 16; return v.f;
}
__device__ __forceinline__ u32t fbits(float f){
  union { float f; u32t u; } c; c.f = f; return c.u;
}
__device__ __forceinline__ u16t bf16bits(float v){
  __hip_bfloat16 b = __float2bfloat16(v);
  union { __hip_bfloat16 b; u16t u; } c; c.b = b; return c.u;
}
template<bool F32>
__device__ __forceinline__ float ldE(const void* p, int i){
  if (F32) return ((const float*)p)[i];
  return bfu(((const u16t*)p)[i]);
}
template<bool F32>
__device__ __forceinline__ u16t ldB(const void* p, int i){
  if (F32) return bf16bits(((const float*)p)[i]);
  return ((const u16t*)p)[i];
}
template<bool F32>
__device__ __forceinline__ void stO(void* p, int i, float v){
  if (F32) ((float*)p)[i] = v;
  else     ((u16t*)p)[i] = bf16bits(v);
}
__device__ __forceinline__ float sigm(float x){ return 1.f / (1.f + __expf(-x)); }
__device__ __forceinline__ float tanhx(float x){
  float e = __expf(-2.f * fabsf(x));
  float t = (1.f - e) / (1.f + e);
  return copysignf(t, x);
}
// Escalating backoff (round-8 proven): free for first probes, then sleep.
__device__ __forceinline__ void backoff(int sp){
  if (sp > 8)      __builtin_amdgcn_s_sleep(8);   // ~213ns
  else if (sp > 2) __builtin_amdgcn_s_sleep(2);   // ~53ns
}
// Tagged-pair store: (value, epoch) as one 64-bit agent-scope atomic store.
__device__ __forceinline__ void stp(float* rowbase, int idx, float v, u32t ep){
  u64t u = (u64t)fbits(v) | ((u64t)ep << 32);
  __hip_atomic_store((u64t*)rowbase + idx, u,
                     __ATOMIC_RELAXED, __HIP_MEMORY_SCOPE_AGENT);
}
// Coherent 16B load (device coherence point).
__device__ __forceinline__ float4 ld4c(const float* p){
  float4 r;
  asm volatile("global_load_dwordx4 %0, %1, off sc0 sc1\n\t"
               "s_waitcnt vmcnt(0)"
               : "=&v"(r) : "v"(p) : "memory");
  return r;
}
// Two coherent 16B loads, single wait.
__device__ __forceinline__ void ld4c2(const float* p0, const float* p1,
                                      float4& a, float4& b){
  asm volatile(
    "global_load_dwordx4 %0, %2, off sc0 sc1\n\t"
    "global_load_dwordx4 %1, %3, off sc0 sc1\n\t"
    "s_waitcnt vmcnt(0)"
    : "=&v"(a), "=&v"(b)
    : "v"(p0), "v"(p1)
    : "memory");
}
// Poll one quad (2 tagged pairs) until both tags == ep.
__device__ __forceinline__ float2 poll2(const float* q, u32t ep, int* bail){
  float4 r; int sp = 0;
  for (;;){
    r = ld4c(q);
    if (fbits(r.y) == ep && fbits(r.w) == ep) break;
    if (*bail) break;
    if (++sp > SPINCAP){ *bail = 1; break; }
    backoff(sp);
  }
  return float2{r.x, r.z};
}

// Half-wave (32 lanes) dot of GLOBAL weight row with f32 x (LDS).
template<bool F32>
__device__ __forceinline__ float hw_dot(const void* wbase, long off,
                                        const float* __restrict__ x,
                                        int K, int lane){
  float acc = 0.f;
  if (F32){
    const float* w = (const float*)wbase + off;
    for (int c = lane * 4; c < K; c += 128){
      float4 wv = *(const float4*)(w + c);
      float4 xv = *(const float4*)(x + c);
      acc = fmaf(wv.x, xv.x, acc); acc = fmaf(wv.y, xv.y, acc);
      acc = fmaf(wv.z, xv.z, acc); acc = fmaf(wv.w, xv.w, acc);
    }
  } else {
    const u16t* w = (const u16t*)wbase + off;
    for (int c = lane * 4; c < K; c += 128){
      ushort4 wv = *(const ushort4*)(w + c);
      float4  xv = *(const float4*)(x + c);
      acc = fmaf(bfu(wv.x), xv.x, acc); acc = fmaf(bfu(wv.y), xv.y, acc);
      acc = fmaf(bfu(wv.z), xv.z, acc); acc = fmaf(bfu(wv.w), xv.w, acc);
    }
  }
  #pragma unroll
  for (int o = 16; o; o >>= 1) acc += __shfl_xor(acc, o, 64);
  return acc;
}

// Un-reduced per-lane dot partials (half-wave, 32 lanes); reduce with wred.
__device__ __forceinline__ float dotnr_f32(const float* __restrict__ w,
                                           const float* __restrict__ x,
                                           int K, int lane){
  float acc = 0.f;
  for (int c = lane * 4; c < K; c += 128){
    float4 wv = *(const float4*)(w + c);
    float4 xv = *(const float4*)(x + c);
    acc = fmaf(wv.x, xv.x, acc); acc = fmaf(wv.y, xv.y, acc);
    acc = fmaf(wv.z, xv.z, acc); acc = fmaf(wv.w, xv.w, acc);
  }
  return acc;
}
__device__ __forceinline__ float dotnr_bf16(const u16t* __restrict__ w,
                                            const float* __restrict__ x,
                                            int K, int lane){
  float acc = 0.f;
  for (int c = lane * 8; c < K; c += 256){
    uint4  wv = *(const uint4*)(w + c);
    float4 x0 = *(const float4*)(x + c);
    float4 x1 = *(const float4*)(x + c + 4);
    acc = fmaf(bfu((u16t)(wv.x & 0xffff)), x0.x, acc);
    acc = fmaf(bfu((u16t)(wv.x >> 16)),    x0.y, acc);
    acc = fmaf(bfu((u16t)(wv.y & 0xffff)), x0.z, acc);
    acc = fmaf(bfu((u16t)(wv.y >> 16)),    x0.w, acc);
    acc = fmaf(bfu((u16t)(wv.z & 0xffff)), x1.x, acc);
    acc = fmaf(bfu((u16t)(wv.z >> 16)),    x1.y, acc);
    acc = fmaf(bfu((u16t)(wv.w & 0xffff)), x1.z, acc);
    acc = fmaf(bfu((u16t)(wv.w >> 16)),    x1.w, acc);
  }
  return acc;
}
__device__ __forceinline__ float wred(float a){
  #pragma unroll
  for (int o = 16; o; o >>= 1) a += __shfl_xor(a, o, 64);
  return a;
}
__device__ __forceinline__ float lds_dot_bf16(const u16t* __restrict__ w,
                                              const float* __restrict__ x,
                                              int K, int lane){
  return wred(dotnr_bf16(w, x, K, lane));
}

// Direct ds/f production: 16 outputs o=(w&7)*16+hw from the dh broadcast
// staged in LDS (xs[1024:2048]); weights from the self-staged bf16 rows.
template<bool F32>
__device__ __forceinline__ void produce_sf(const Params& p, float* ws,
                                           const u16t* __restrict__ myrow,
                                           SharedMem& S, int ph, int par,
                                           u32t ep, int t, int w, int hw,
                                           int lane){
  const int o = (w & 7) * 16 + hw;
  float* sf = ws + SFF + (par * 3 + ph) * 256;
  float s = hw_dot<false>(myrow, 0, S.xs + 1024, 1024, lane);
  if (o < 64){
    s += S.clsb[o];
    if (lane == 0){
      stO<F32>(p.out, TSTEPS * 64 + (t * 3 + ph) * 64 + o, s);
      if (ph < 2) stp(sf, o, s, ep);
    }
  } else {
    s = fmaxf(s + S.futb[o - 64], 0.f);
    if (lane == 0) stp(sf, o, s, ep);
  }
}

template<bool F32>
__device__ void run(const Params& p, SharedMem& S){
  const int tid  = threadIdx.x;
  const int w    = blockIdx.x;
  const int hw   = tid >> 5;            // half-wave 0..15 -> one gate row each
  const int lane = tid & 31;
  const long grow = (long)((hw >> 2) * 1024 + 4 * w + (hw & 3));  // gate row
  float* ws = p.ws;
  u16t* bcw = (u16t*)(ws + BCW);

  // ---------- startup: stage per-WG weights into LDS ----------
  {
    float* ei = S.encWih + hw * 128;
    for (int c = lane; c < 128; c += 32)  ei[c] = ldE<F32>(p.eWih, (int)(grow * 128 + c));
    u16t* eh = S.encWhh + hw * 1024;
    for (int c = lane; c < 1024; c += 32) eh[c] = ldB<F32>(p.eWhh, (int)(grow * 1024 + c));
    u16t* dr = S.decW + hw * 2048;
    for (int c = lane; c < 1024; c += 32){
      dr[c]        = ldB<F32>(p.dWih, (int)(grow * 1024 + c));
      dr[1024 + c] = ldB<F32>(p.dWhh, (int)(grow * 1024 + c));
    }
  }
  // headW: hxW rows(0-3) | cxW rows(4-7) for this WG's 4 hidden units
  for (int i = tid; i < 8192; i += NTHR){
    int r = i >> 10, c = i & 1023;
    S.headW[i] = (r < 4) ? ldB<F32>(p.hxW, (4 * w + r) * 1024 + c)
                         : ldB<F32>(p.cxW, (4 * w + (r - 4)) * 1024 + c);
  }
  // producer WGs: self-stage 16 clsW/futW rows as bf16 in workspace
  const u16t* myrow = nullptr;
  if (w >= 16 && w < 40){
    const int slot = (w - 16) * 16 + hw;
    const int o = (w & 7) * 16 + hw;
    const void* src = (o < 64) ? p.clsW : p.futW;
    const int row = (o < 64) ? o : o - 64;
    u16t* dst = bcw + (size_t)slot * 1024;
    for (int c = lane; c < 1024; c += 32)
      dst[c] = ldB<F32>(src, row * 1024 + c);
    myrow = dst;
  }
  // fus_W rows for this thread's two h outputs -> registers (proven: no spill)
  u32t fw[64];
  float fusb0, fusb1;
  {
    int h0 = 2 * tid, h1 = 2 * tid + 1;
    #pragma unroll
    for (int o = 0; o < 64; ++o){
      u16t lo = ldB<F32>(p.fusW, h0 * 64 + o);
      u16t hi = ldB<F32>(p.fusW, h1 * 64 + o);
      fw[o] = ((u32t)hi << 16) | lo;
    }
    fusb0 = ldE<F32>(p.fusb_g, h0);
    fusb1 = ldE<F32>(p.fusb_g, h1);
  }
  if (tid < 64){
    S.clsb[tid] = ldE<F32>(p.clsb_g, tid);
    S.futb[tid] = ldE<F32>(p.futb_g, tid);
    S.fut_acc[tid] = 0.f;
  }
  if (tid < 16){
    int gr = (tid >> 2) * 1024 + 4 * w + (tid & 3);
    S.bias_e[tid] = ldE<F32>(p.ebih, gr) + ldE<F32>(p.ebhh, gr);
    S.bias_d[tid] = ldE<F32>(p.dbih, gr) + ldE<F32>(p.dbhh, gr);
  }
  if (tid < 4){
    S.hxb4[tid] = ldE<F32>(p.hxb, 4 * w + tid);
    S.cxb4[tid] = ldE<F32>(p.cxb, 4 * w + tid);
    S.encc[tid] = 0.f;
  }
  float enc_pre = 0.f;   // per-lane partial of encWhh @ h(t-1); h(-1)=0
  __syncthreads();

  for (int t = 0; t < TSTEPS; ++t){
    const int  par  = t & 1;
    const int  ppar = par ^ 1;
    const u32t ep   = (u32t)(t + 1);
    const u32t epv  = (u32t)t;            // tag of previous step's values

    // ============ R1: encoder gates (h part carried in enc_pre) ============
    if (t > 0 && tid < 32){               // f3 pairs: SF[ppar][ph2] quads 32..63
      const float* base = ws + SFF + (ppar * 3 + 2) * 256;
      float2 v = poll2(base + (32 + tid) * 4, epv, &S.bail);
      S.fv3[2 * tid] = v.x; S.fv3[2 * tid + 1] = v.y;
    }
    __syncthreads();
    if (tid < 64){
      S.xsf[tid] = (t == 0) ? ldE<F32>(p.X, tid) : S.xnext[tid];
      float fv = (t > 0) ? (S.fut_acc[tid] + S.fv3[tid]) * (1.f / 3.f) : 0.f;
      S.xsf[64 + tid] = fv;
      S.fut_acc[tid] = 0.f;
    }
    __syncthreads();
    {
      float a = wred(enc_pre + dotnr_f32(S.encWih + hw * 128, S.xsf, 128, lane))
              + S.bias_e[hw];
      if (lane == 0) S.g16[hw] = a;
    }
    __syncthreads();
    if (tid < 4){
      float gi = sigm(S.g16[tid]), gf = sigm(S.g16[4 + tid]),
            gg = tanhx(S.g16[8 + tid]), go = sigm(S.g16[12 + tid]);
      float c = gf * S.encc[tid] + gi * gg;
      float h = go * tanhx(c);
      S.encc[tid] = c;
      stp(ws + HENC + par * 2048, 4 * w + tid, h, ep);
      stp(ws + CENC + par * 2048, 4 * w + tid, c, ep);
    }

    // ============ R2: merged h+c poll; heads dhx/dcx; enc_score; enc_pre ====
    {
      const float* ph_ = ws + HENC + par * 2048 + tid * 4;
      const float* pc_ = ws + CENC + par * 2048 + tid * 4;
      float4 a, b; int sp = 0;
      for (;;){
        ld4c2(ph_, pc_, a, b);
        if (fbits(a.y) == ep && fbits(a.w) == ep &&
            fbits(b.y) == ep && fbits(b.w) == ep) break;
        if (S.bail) break;
        if (++sp > SPINCAP){ S.bail = 1; break; }
        backoff(sp);
      }
      S.xs[2 * tid] = a.x;        S.xs[2 * tid + 1] = a.z;
      S.xs[1024 + 2 * tid] = b.x; S.xs[1025 + 2 * tid] = b.z;
    }
    __syncthreads();
    if (hw < 4){
      float d = fmaxf(lds_dot_bf16(S.headW + hw * 1024, S.xs, 1024, lane)
                      + S.hxb4[hw], 0.f);
      if (lane == 0) stp(ws + DHX + par * 2048, 4 * w + hw, d, ep);
    } else if (hw < 8){
      int j = hw - 4;
      float d = fmaxf(lds_dot_bf16(S.headW + (4 + j) * 1024, S.xs + 1024, 1024, lane)
                      + S.cxb4[j], 0.f);
      if (lane == 0) S.dcx_s[j] = d;   // decoder c, reused by all 3 iters (ref bug)
    } else if (w >= 8 && w < 16){      // enc_score: 8 WGs x 8 half-waves
      int r = (w - 8) * 8 + (hw - 8);
      float s = hw_dot<F32>(p.clsW, (long)r * 1024, S.xs, 1024, lane) + S.clsb[r];
      if (lane == 0) stO<F32>(p.out, t * 64 + r, s);
    }
    // next step's encoder Whh@h partial, in R2's shadow (after DHX stp)
    enc_pre = dotnr_bf16(S.encWhh + hw * 1024, S.xs, 1024, lane);
    __syncthreads();   // protect xs readers (enc_score/dcx) from R3 overwrite

    // ============ R3: decoder iter 1 (fusion_in = 0) ============
    {
      float2 v = poll2(ws + DHX + par * 2048 + tid * 4, ep, &S.bail);
      S.xs[2 * tid] = v.x; S.xs[2 * tid + 1] = v.y;
    }
    __syncthreads();
    {
      float a = lds_dot_bf16(S.decW + hw * 2048 + 1024, S.xs, 1024, lane) + S.bias_d[hw];
      if (lane == 0) S.g16[hw] = a;
    }
    __syncthreads();
    if (tid < 4){
      float gi = sigm(S.g16[tid]), gf = sigm(S.g16[4 + tid]),
            gg = tanhx(S.g16[8 + tid]), go = sigm(S.g16[12 + tid]);
      float c = gf * S.dcx_s[tid] + gi * gg;
      float h = go * tanhx(c);
      stp(ws + DD1 + par * 2048, 4 * w + tid, h, ep);
    }
    if (tid < 64)
      S.xnext[tid] = ldE<F32>(p.X, (t + 1) * 64 + tid);   // prefetch x(t+1)

    // ============ R4/R5: decoder iters 2,3 ============
    for (int di = 2; di <= 3; ++di){
      const int ph = di - 2;               // sf phase produced this round
      // stage dh_{di-1} -> xs[1024:2048]
      {
        const float* dbuf = ws + (di == 2 ? DD1 : DD2) + par * 2048;
        float2 v = poll2(dbuf + tid * 4, ep, &S.bail);
        S.xs[1024 + 2 * tid] = v.x; S.xs[1025 + 2 * tid] = v.y;
      }
      __syncthreads();
      // ds/f producers FIRST (critical path for everyone's fusion)
      if (w >= 16 + ph * 8 && w < 24 + ph * 8)
        produce_sf<F32>(p, ws, myrow, S, ph, par, ep, t, w, hw, lane);
      float accA = lds_dot_bf16(S.decW + hw * 2048 + 1024, S.xs + 1024, 1024, lane);
      // poll ds/f broadcast
      if (tid < 64){
        const float* sf = ws + SFF + (par * 3 + ph) * 256;
        float2 v = poll2(sf + tid * 4, ep, &S.bail);
        if (tid < 32){ S.dsbuf[2 * tid] = v.x; S.dsbuf[2 * tid + 1] = v.y; }
        else { S.fv3[2 * (tid - 32)] = v.x; S.fv3[2 * (tid - 32) + 1] = v.y; }
      }
      __syncthreads();
      if (tid < 64) S.fut_acc[tid] += S.fv3[tid];
      {   // fusion_in = relu(fus_W @ ds + fus_b), per-thread 2 rows from VGPRs
        float a0 = fusb0, a1 = fusb1;
        #pragma unroll
        for (int o = 0; o < 64; ++o){
          float d = S.dsbuf[o];
          a0 = fmaf(bfu((u16t)(fw[o] & 0xffff)), d, a0);
          a1 = fmaf(bfu((u16t)(fw[o] >> 16)),    d, a1);
        }
        S.xs[2 * tid]     = fmaxf(a0, 0.f);
        S.xs[2 * tid + 1] = fmaxf(a1, 0.f);
      }
      __syncthreads();
      float accB = lds_dot_bf16(S.decW + hw * 2048, S.xs, 1024, lane);
      {
        float a = accA + accB + S.bias_d[hw];
        if (lane == 0) S.g16[hw] = a;
      }
      __syncthreads();
      if (tid < 4){
        float gi = sigm(S.g16[tid]), gf = sigm(S.g16[4 + tid]),
              gg = tanhx(S.g16[8 + tid]), go = sigm(S.g16[12 + tid]);
        float c = gf * S.dcx_s[tid] + gi * gg;
        float h = go * tanhx(c);
        stp(ws + (di == 2 ? DD2 : DD3) + par * 2048, 4 * w + tid, h, ep);
      }
    }
    // ph2 producers: poll DD3, compute ds3 (-> out) and f3 (-> next R1's SFF)
    if (w >= 32 && w < 40){
      {
        float2 v = poll2(ws + DD3 + par * 2048 + tid * 4, ep, &S.bail);
        S.xs[1024 + 2 * tid] = v.x; S.xs[1025 + 2 * tid] = v.y;
      }
      __syncthreads();
      produce_sf<F32>(p, ws, myrow, S, 2, par, ep, t, w, hw, lane);
    }
  }
}

__global__ __launch_bounds__(NTHR, 2)
void trn_persist(Params p){
  __shared__ SharedMem S;
  // ---- runtime input-dtype detection from X's bit patterns ----
  if (threadIdx.x == 0){ S.bail = 0; S.badcnt = 0; }
  __syncthreads();
  if (threadIdx.x < 256){
    u16t u = ((const u16t*)p.X)[threadIdx.x];
    int e = (u >> 7) & 0xff;
    if (e == 0 || e >= 141) atomicAdd(&S.badcnt, 1);
  }
  __syncthreads();
  if (S.badcnt >= 3) run<true>(p, S);
  else               run<false>(p, S);
}

extern "C" void kernel_launch(void* const* d_in, const int* in_sizes, int n_in,
                              void* d_out, int out_size, void* d_ws, size_t ws_size,
                              hipStream_t stream){
  Params P;
  P.X      = d_in[0];
  P.eWih   = d_in[1];
  P.eWhh   = d_in[2];
  P.ebih   = d_in[3];
  P.ebhh   = d_in[4];
  P.dWih   = d_in[5];
  P.dWhh   = d_in[6];
  P.dbih   = d_in[7];
  P.dbhh   = d_in[8];
  P.hxW    = d_in[9];
  P.hxb    = d_in[10];
  P.cxW    = d_in[11];
  P.cxb    = d_in[12];
  P.fusW   = d_in[13];
  P.fusb_g = d_in[14];
  P.futW   = d_in[15];
  P.futb_g = d_in[16];
  P.clsW   = d_in[17];
  P.clsb_g = d_in[18];
  P.ws     = (float*)d_ws;
  P.out    = d_out;

  void* args[] = { &P };
  hipLaunchCooperativeKernel((void*)trn_persist, dim3(NWG), dim3(NTHR),
                             args, 0, stream);
}